// Round 13
// baseline (244.275 us; speedup 1.0000x reference)
//
#include <hip/hip_runtime.h>
#include <hip/hip_bf16.h>

#define NBR   8
#define DV    256    // VOCAB
#define FF    1024   // FFN
#define RT    64     // rows per block
#define NCH   16     // FFN chunks of 64
#define NROWS 16384

// LDS: B1 dbuf 2x32K @0 | Hs dbuf 2x8K @64K = 80K -> 2 blocks/CU
#define L_B1 0
#define L_HS 65536
#define LDS_BYTES 81920

using bf16x8 = __attribute__((ext_vector_type(8))) short;
using f32x4  = __attribute__((ext_vector_type(4))) float;

__device__ __forceinline__ unsigned short f2bf(float f) {
    unsigned int u = __builtin_bit_cast(unsigned int, f);
    unsigned int r = (u + 0x7fffu + ((u >> 16) & 1u)) >> 16;
    return (unsigned short)r;
}
// gelu(x) ~= x * sigmoid(1.595769122x + 0.0713548163x^3), exp2 domain
__device__ __forceinline__ float gelu_fast(float x) {
    float x2 = x * x;
    float z  = x * fmaf(x2, -0.1029434959f, -2.3022078770f);
    float e  = __builtin_amdgcn_exp2f(z);
    return x * __builtin_amdgcn_rcpf(1.0f + e);
}

#define GLL(gsrc, ldst) __builtin_amdgcn_global_load_lds((const unsigned int*)(gsrc), (unsigned int*)(ldst), 16, 0, 0)
#define MFMA16 __builtin_amdgcn_mfma_f32_16x16x32_bf16

// ---------------- prep ----------------
// img1 per (n,cch) [32KB], cch in [0,16): slot p in [0,2048): kkg=p>>6, nn=p&63
//   byte p*16, elem j = U1[n][kkg*8+j][cch*64+nn]
// img2 per (n,cch) [32KB]: 32 frags (16x16x32 B-frag) of 1KB; frag f = ks*16+cfg:
//   at (f<<10)+l*16, elem j = U2[n][cch*64 + ks*32 + (l>>4)*8 + j][cfg*16 + (l&15)]
__global__ void prep_weights(const float* __restrict__ U1, const float* __restrict__ U2,
                             unsigned short* __restrict__ w1img, unsigned short* __restrict__ w2img)
{
    const int b = blockIdx.x;          // 0..127 = n*16 + cch
    const int n = b >> 4, cch = b & 15;
    const int tid = threadIdx.x;       // 0..255
    char* img1 = (char*)w1img + ((size_t)b << 15);
    char* img2 = (char*)w2img + ((size_t)b << 15);
    const float* U1n = U1 + (size_t)n * DV * FF;
    const float* U2n = U2 + (size_t)n * FF * DV;
    #pragma unroll
    for (int e = 0; e < 8; ++e) {
        int p = tid + e * 256;         // 0..2047
        int kkg = p >> 6, nn = p & 63;
        bf16x8 h;
        #pragma unroll
        for (int j = 0; j < 8; ++j)
            h[j] = (short)f2bf(U1n[(size_t)(kkg * 8 + j) * FF + cch * 64 + nn]);
        *(bf16x8*)(img1 + ((size_t)p << 4)) = h;
    }
    #pragma unroll
    for (int e = 0; e < 8; ++e) {
        int p = tid + e * 256;         // 0..2047 = f*64 + l
        int f = p >> 6, l = p & 63;
        int ks = f >> 4, cfg = f & 15;
        bf16x8 h;
        #pragma unroll
        for (int j = 0; j < 8; ++j)
            h[j] = (short)f2bf(U2n[(size_t)(cch * 64 + ks * 32 + (l >> 4) * 8 + j) * DV + cfg * 16 + (l & 15)]);
        *(bf16x8*)(img2 + ((size_t)p << 4)) = h;
    }
}

// ---------------- main: chunk=64, ONE barrier/chunk, G2[t-1] merged into phase t ----------------
__global__ __launch_bounds__(512, 4)
void belayer_main(const float* __restrict__ x,
                  const unsigned short* __restrict__ w1img,
                  const unsigned short* __restrict__ w2img,
                  const float* __restrict__ b1g, const float* __restrict__ b2g,
                  const float* __restrict__ lnw, const float* __restrict__ lnb,
                  float* __restrict__ out)
{
    __shared__ __align__(16) char LDS[LDS_BYTES];
    const int tid  = threadIdx.x;
    const int lane = tid & 63;
    const int wave = tid >> 6;          // 0..7
    const int q = lane >> 4, c = lane & 15;
    const int n    = blockIdx.x & 7;    // branch == XCD affinity
    const int tile = blockIdx.x >> 3;   // 0..255
    const int row0 = tile * RT;
    const int rowg   = wave >> 1;       // G1: rows rowg*16
    const int colsel = wave & 1;        // G1: ffn 32-col half of chunk
    const int rowg2  = wave >> 2;       // G2: rows rowg2*32
    const int colg2  = wave & 3;        // G2: cols colg2*64

    const char* g1base = (const char*)w1img + ((size_t)(n * NCH) << 15) + (wave << 12) + lane * 16;
    const char* g2base = (const char*)w2img + ((size_t)(n * NCH) << 15) + ((unsigned)(colg2 * 4) << 10) + lane * 16;
    char* l1base = LDS + L_B1 + (wave << 12);

#define STAGE1(T) do { const char* g_ = g1base + ((size_t)(T) << 15); \
        char* l_ = l1base + (((T) & 1) << 15); \
        GLL(g_, l_); GLL(g_ + 1024, l_ + 1024); GLL(g_ + 2048, l_ + 2048); GLL(g_ + 3072, l_ + 3072); } while (0)

    STAGE1(0);

    // ---- A-frags resident (32 VGPR): row = rowg*16 + c, kk = ks*32 + q*8 ----
    bf16x8 A[8];
    {
        const float* src = x + (((size_t)(row0 + rowg * 16 + c)) * NBR + n) * DV + q * 8;
        #pragma unroll
        for (int ks = 0; ks < 8; ++ks) {
            f32x4 v0 = *(const f32x4*)(src + ks * 32);
            f32x4 v1 = *(const f32x4*)(src + ks * 32 + 4);
            bf16x8 h;
            h[0] = (short)f2bf(v0[0]); h[1] = (short)f2bf(v0[1]);
            h[2] = (short)f2bf(v0[2]); h[3] = (short)f2bf(v0[3]);
            h[4] = (short)f2bf(v1[0]); h[5] = (short)f2bf(v1[1]);
            h[6] = (short)f2bf(v1[2]); h[7] = (short)f2bf(v1[3]);
            A[ks] = h;
        }
    }

    // ---- LDS addresses ----
    // B1 image in LDS: [32 kgrp][64 nn][8k]; read (ks,q) -> kgrp = ks*4+q
    const unsigned aB1 = (unsigned)((colsel * 32 + c) * 16);      // + (ks*4+q)*1024 + cf*256
    // Hs [8 kgrp][64 row][8k] (8KB per buffer)
    unsigned aWb[2];
    #pragma unroll
    for (int cf = 0; cf < 2; ++cf)
        aWb[cf] = (unsigned)(((colsel * 4 + cf * 2 + (c >> 3)) * 64 + rowg * 16 + q * 4) * 16 + (c & 7) * 2);
    const unsigned aH = (unsigned)((q * 64 + rowg2 * 32 + c) * 16);   // + ks*4096 + rf*256

    f32x4 acc2[2][4];
    #pragma unroll
    for (int i = 0; i < 2; ++i)
        #pragma unroll
        for (int j = 0; j < 4; ++j) acc2[i][j] = (f32x4){0.f, 0.f, 0.f, 0.f};

    __syncthreads();   // B1[0] staged & visible

    for (int t = 0; t <= NCH; ++t) {
        // ---- B2 frags for G2[t-1]: global(L2)->VGPR, issued first (latency hides under G1) ----
        bf16x8 B2f[2][4];
        if (t >= 1) {
            #pragma unroll
            for (int ks = 0; ks < 2; ++ks)
                #pragma unroll
                for (int cf = 0; cf < 4; ++cf)
                    B2f[ks][cf] = *(const bf16x8*)(g2base + ((size_t)(t - 1) << 15) + (ks << 14) + (cf << 10));
        }
        if (t + 1 < NCH) STAGE1(t + 1);

        // ---- G1[t]: 16 ds_read + 16 MFMA + gelu -> Hs[t&1] ----
        if (t < NCH) {
            float b1v0 = b1g[n * FF + t * 64 + colsel * 32 + c];
            float b1v1 = b1g[n * FF + t * 64 + colsel * 32 + 16 + c];
            const unsigned h1 = L_B1 + ((unsigned)(t & 1) << 15);
            f32x4 acc1[2];
            acc1[0] = (f32x4){0.f, 0.f, 0.f, 0.f};
            acc1[1] = (f32x4){0.f, 0.f, 0.f, 0.f};
            #pragma unroll
            for (int ks = 0; ks < 8; ++ks) {
                const unsigned base = h1 + (unsigned)(ks * 4 + q) * 1024 + aB1;
                bf16x8 b0 = *(const bf16x8*)(LDS + base);
                bf16x8 b1 = *(const bf16x8*)(LDS + base + 256);
                acc1[0] = MFMA16(A[ks], b0, acc1[0], 0, 0, 0);
                acc1[1] = MFMA16(A[ks], b1, acc1[1], 0, 0, 0);
            }
            const unsigned hw = L_HS + ((unsigned)(t & 1) << 13);
            #pragma unroll
            for (int cf = 0; cf < 2; ++cf) {
                float bv = cf ? b1v1 : b1v0;
                #pragma unroll
                for (int r = 0; r < 4; ++r) {
                    float g = gelu_fast(acc1[cf][r] + bv);
                    *(unsigned short*)(LDS + hw + aWb[cf] + r * 16) = f2bf(g);
                }
            }
        }

        // ---- G2[t-1]: 4 ds_read (Hs[(t-1)&1]) + 16 MFMA (B from regs) ----
        if (t >= 1) {
            const unsigned hp = L_HS + ((unsigned)((t - 1) & 1) << 13);
            #pragma unroll
            for (int ks = 0; ks < 2; ++ks) {
                bf16x8 a0 = *(const bf16x8*)(LDS + hp + aH + ks * 4096);
                bf16x8 a1 = *(const bf16x8*)(LDS + hp + aH + ks * 4096 + 256);
                #pragma unroll
                for (int cf = 0; cf < 4; ++cf) {
                    acc2[0][cf] = MFMA16(a0, B2f[ks][cf], acc2[0][cf], 0, 0, 0);
                    acc2[1][cf] = MFMA16(a1, B2f[ks][cf], acc2[1][cf], 0, 0, 0);
                }
            }
        }
        __syncthreads();   // publish Hs[t] + B1[t+1]; Hs[t-1] readers done
    }

    // ---- epilogue: +b2, LN(256), gelu, +skip ----
    float b2v[4];
    #pragma unroll
    for (int cf = 0; cf < 4; ++cf) b2v[cf] = b2g[n * DV + colg2 * 64 + cf * 16 + c];

    float sA[2][4], sQ[2][4];
    #pragma unroll
    for (int rf = 0; rf < 2; ++rf)
        #pragma unroll
        for (int r = 0; r < 4; ++r) { sA[rf][r] = 0.f; sQ[rf][r] = 0.f; }
    #pragma unroll
    for (int rf = 0; rf < 2; ++rf)
        #pragma unroll
        for (int cf = 0; cf < 4; ++cf)
            #pragma unroll
            for (int r = 0; r < 4; ++r) {
                float v = acc2[rf][cf][r] + b2v[cf];
                acc2[rf][cf][r] = v;
                sA[rf][r] += v;
                sQ[rf][r] += v * v;
            }
    #pragma unroll
    for (int m = 1; m < 16; m <<= 1)
        #pragma unroll
        for (int rf = 0; rf < 2; ++rf)
            #pragma unroll
            for (int r = 0; r < 4; ++r) {
                sA[rf][r] += __shfl_xor(sA[rf][r], m, 64);
                sQ[rf][r] += __shfl_xor(sQ[rf][r], m, 64);
            }
    // partials Lred[row*4 + colg2] (s), +256 floats (sq): 2KB at Hs[0] (last G2 read Hs[1])
    float* Lred = (float*)(LDS + L_HS);
    if (c == 0) {
        #pragma unroll
        for (int rf = 0; rf < 2; ++rf)
            #pragma unroll
            for (int r = 0; r < 4; ++r) {
                int row = rowg2 * 32 + rf * 16 + q * 4 + r;
                Lred[row * 4 + colg2]       = sA[rf][r];
                Lred[256 + row * 4 + colg2] = sQ[rf][r];
            }
    }
    __syncthreads();
    float mu[2][4], rs[2][4];
    #pragma unroll
    for (int rf = 0; rf < 2; ++rf)
        #pragma unroll
        for (int r = 0; r < 4; ++r) {
            int row = rowg2 * 32 + rf * 16 + q * 4 + r;
            f32x4 sv = *(const f32x4*)(Lred + row * 4);
            f32x4 qv = *(const f32x4*)(Lred + 256 + row * 4);
            float ssum = sv[0] + sv[1] + sv[2] + sv[3];
            float qsum = qv[0] + qv[1] + qv[2] + qv[3];
            float m_ = ssum * (1.0f / 256.0f);
            float var = qsum * (1.0f / 256.0f) - m_ * m_;
            mu[rf][r] = m_;
            rs[rf][r] = rsqrtf(var + 1e-5f);
        }
    #pragma unroll
    for (int cf = 0; cf < 4; ++cf) {
        int col = colg2 * 64 + cf * 16 + c;
        float lw = lnw[col];
        float lb = lnb[col];
        #pragma unroll
        for (int rf = 0; rf < 2; ++rf)
            #pragma unroll
            for (int r = 0; r < 4; ++r) {
                int row = rowg2 * 32 + rf * 16 + q * 4 + r;
                float v = (acc2[rf][cf][r] - mu[rf][r]) * rs[rf][r] * lw + lb;
                float g = gelu_fast(v);
                size_t oi = ((size_t)(row0 + row) * NBR + n) * DV + col;
                out[oi] = x[oi] + g;
            }
    }
#undef STAGE1
}

extern "C" void kernel_launch(void* const* d_in, const int* in_sizes, int n_in,
                              void* d_out, int out_size, void* d_ws, size_t ws_size,
                              hipStream_t stream) {
    const float* x   = (const float*)d_in[0];
    const float* U1  = (const float*)d_in[1];
    const float* b1  = (const float*)d_in[2];
    const float* U2  = (const float*)d_in[3];
    const float* b2  = (const float*)d_in[4];
    const float* lnw = (const float*)d_in[5];
    const float* lnb = (const float*)d_in[6];
    float* out = (float*)d_out;

    unsigned short* w1img = (unsigned short*)d_ws;               // 4 MB (128 x 32KB)
    unsigned short* w2img = w1img + (size_t)4 * 1024 * 1024 / 2; // 4 MB (128 x 32KB)

    prep_weights<<<dim3(128), dim3(256), 0, stream>>>(U1, U2, w1img, w2img);
    belayer_main<<<dim3((NROWS / RT) * NBR), dim3(512), 0, stream>>>(x, w1img, w2img, b1, b2, lnw, lnb, out);
}

// Round 14
// 228.527 us; speedup vs baseline: 1.0689x; 1.0689x over previous
//
#include <hip/hip_runtime.h>
#include <hip/hip_bf16.h>

#define NBR   8
#define DV    256    // VOCAB
#define FF    1024   // FFN
#define RT    64     // rows per block
#define NCH   32     // FFN chunks of 32
#define NROWS 16384

// LDS: B1 dbuf 2x16K @0 | Hs 4K @32K = 36K  (B2 goes global(L2)->VGPR, no LDS)
#define L_B1 0
#define L_HS 32768
#define LDS_BYTES 36864

using bf16x8 = __attribute__((ext_vector_type(8))) short;
using f32x4  = __attribute__((ext_vector_type(4))) float;
using u32x4  = __attribute__((ext_vector_type(4))) unsigned int;

__device__ __forceinline__ unsigned short f2bf(float f) {     // exact RNE (prep only)
    unsigned int u = __builtin_bit_cast(unsigned int, f);
    unsigned int r = (u + 0x7fffu + ((u >> 16) & 1u)) >> 16;
    return (unsigned short)r;
}
__device__ __forceinline__ unsigned int f2bf_rhu(float f) {   // round-half-up, 2 ops
    return (__builtin_bit_cast(unsigned int, f) + 0x8000u) >> 16;
}
// pack two floats -> bf16x2 (round-half-up): 2 v_add + 1 v_perm
__device__ __forceinline__ unsigned int pk_bf2(float a, float b) {
    unsigned int ua = __builtin_bit_cast(unsigned int, a) + 0x8000u;
    unsigned int ub = __builtin_bit_cast(unsigned int, b) + 0x8000u;
    return __builtin_amdgcn_perm(ub, ua, 0x07060302u);   // [ua.b2,ua.b3,ub.b2,ub.b3]
}
// gelu(x) ~= x * sigmoid(1.595769122x + 0.0713548163x^3), exp2 domain
__device__ __forceinline__ float gelu_fast(float x) {
    float x2 = x * x;
    float z  = x * fmaf(x2, -0.1029434959f, -2.3022078770f);
    float e  = __builtin_amdgcn_exp2f(z);
    return x * __builtin_amdgcn_rcpf(1.0f + e);
}

#define GLL(gsrc, ldst) __builtin_amdgcn_global_load_lds((const unsigned int*)(gsrc), (unsigned int*)(ldst), 16, 0, 0)
#define MFMA16 __builtin_amdgcn_mfma_f32_16x16x32_bf16

// ---------------- prep (unchanged from R12) ----------------
// img1 per (n,cch) [16KB]: byte kkg*512+nn*16+j*2 = U1[n][kkg*8+j][cch*32+nn]
// img2 per (n,cch) [16KB]: 16 B-frags (16x16x32) of 1KB; frag cfg:
//     at (cfg<<10) + l*16, elem j = U2[n][cch*32 + (l>>4)*8 + j][cfg*16 + (l&15)]
__global__ void prep_weights(const float* __restrict__ U1, const float* __restrict__ U2,
                             unsigned short* __restrict__ w1img, unsigned short* __restrict__ w2img)
{
    const int b = blockIdx.x;          // 0..255 = n*32 + cch
    const int n = b >> 5, cch = b & 31;
    const int tid = threadIdx.x;       // 0..255
    char* img1 = (char*)w1img + ((size_t)b << 14);
    char* img2 = (char*)w2img + ((size_t)b << 14);
    const float* U1n = U1 + (size_t)n * DV * FF;
    const float* U2n = U2 + (size_t)n * FF * DV;
    #pragma unroll
    for (int e = 0; e < 4; ++e) {
        int p = tid + e * 256;         // 0..1023
        int kkg = p >> 5, nn = p & 31;
        bf16x8 h;
        #pragma unroll
        for (int j = 0; j < 8; ++j)
            h[j] = (short)f2bf(U1n[(size_t)(kkg * 8 + j) * FF + cch * 32 + nn]);
        *(bf16x8*)(img1 + kkg * 512 + nn * 16) = h;
    }
    #pragma unroll
    for (int e = 0; e < 4; ++e) {
        int p = tid + e * 256;         // 0..1023 = cfg*64 + l
        int cfg = p >> 6, l = p & 63;
        bf16x8 h;
        #pragma unroll
        for (int j = 0; j < 8; ++j)
            h[j] = (short)f2bf(U2n[(size_t)(cch * 32 + (l >> 4) * 8 + j) * DV + cfg * 16 + (l & 15)]);
        *(bf16x8*)(img2 + (p << 4)) = h;
    }
}

// ---------------- main: R12 structure + instruction diet ----------------
__global__ __launch_bounds__(512, 4)
void belayer_main(const float* __restrict__ x,
                  const unsigned short* __restrict__ w1img,
                  const unsigned short* __restrict__ w2img,
                  const float* __restrict__ b1g, const float* __restrict__ b2g,
                  const float* __restrict__ lnw, const float* __restrict__ lnb,
                  float* __restrict__ out)
{
    __shared__ __align__(16) char LDS[LDS_BYTES];
    const int tid  = threadIdx.x;
    const int lane = tid & 63;
    const int wave = tid >> 6;          // 0..7
    const int q = lane >> 4, c = lane & 15;
    const int n    = blockIdx.x & 7;    // branch == XCD affinity
    const int tile = blockIdx.x >> 3;   // 0..255
    const int row0 = tile * RT;
    const int rowg   = wave >> 1;       // G1: rows rowg*16
    const int colsel = wave & 1;        // G1: ffn 16-col half of chunk
    const int rowg2  = wave >> 2;       // G2: rows rowg2*32 (0..1)
    const int colg2  = wave & 3;        // G2: cols colg2*64

    const char* g1base = (const char*)w1img + ((size_t)(n * NCH) << 14) + (wave << 11) + lane * 16;
    const char* g2img  = (const char*)w2img + ((size_t)(n * NCH) << 14) + (colg2 << 12) + lane * 16;
    char* l1base = LDS + L_B1 + (wave << 11);

#define STAGE1(T) do { const char* g_ = g1base + ((size_t)(T) << 14); \
        char* l_ = l1base + (((T) & 1) << 14); GLL(g_, l_); GLL(g_ + 1024, l_ + 1024); } while (0)

    STAGE1(0);

    // ---- A-frags resident (32 VGPR): row = rowg*16 + c, kk = ks*32 + q*8 ----
    bf16x8 A[8];
    {
        const float* src = x + (((size_t)(row0 + rowg * 16 + c)) * NBR + n) * DV + q * 8;
        #pragma unroll
        for (int ks = 0; ks < 8; ++ks) {
            f32x4 v0 = *(const f32x4*)(src + ks * 32);
            f32x4 v1 = *(const f32x4*)(src + ks * 32 + 4);
            u32x4 d;
            d[0] = pk_bf2(v0[0], v0[1]);
            d[1] = pk_bf2(v0[2], v0[3]);
            d[2] = pk_bf2(v1[0], v1[1]);
            d[3] = pk_bf2(v1[2], v1[3]);
            A[ks] = __builtin_bit_cast(bf16x8, d);
        }
    }

    // ---- LDS addresses ----
    const unsigned aB1 = (unsigned)(q * 512 + (colsel * 16 + c) * 16);   // + buf + ks*2048
    // Hs kgrp-major [4 kgrp][64 row][8 k]
    unsigned aW[4];
    #pragma unroll
    for (int r = 0; r < 4; ++r)
        aW[r] = (unsigned)(((colsel * 2 + (c >> 3)) * 64 + rowg * 16 + q * 4 + r) * 16 + (c & 7) * 2);
    const unsigned aH = (unsigned)((q * 64 + rowg2 * 32 + c) * 16);      // + rf*256

    // ---- acc2 init = b2 bias (folds the epilogue +b2 pass into MFMA C-in) ----
    float b2v[4];
    #pragma unroll
    for (int cf = 0; cf < 4; ++cf) b2v[cf] = b2g[n * DV + colg2 * 64 + cf * 16 + c];
    f32x4 acc2[2][4];
    #pragma unroll
    for (int i = 0; i < 2; ++i)
        #pragma unroll
        for (int j = 0; j < 4; ++j)
            acc2[i][j] = (f32x4){b2v[j], b2v[j], b2v[j], b2v[j]};

    __syncthreads();   // B1[0] staged & visible

    for (int t = 0; t < NCH; ++t) {
        const unsigned h1 = L_B1 + ((unsigned)(t & 1) << 14);

        // ===== PH_A: B2 frag prefetch (L2->VGPR) ; stage B1[t+1] ; G1 ; gelu->Hs =====
        bf16x8 B2f[4];
        #pragma unroll
        for (int cf = 0; cf < 4; ++cf)
            B2f[cf] = *(const bf16x8*)(g2img + ((size_t)t << 14) + (cf << 10));
        if (t + 1 < NCH) STAGE1(t + 1);
        float b1v = b1g[n * FF + t * 32 + colsel * 16 + c];
        f32x4 acc1 = (f32x4){b1v, b1v, b1v, b1v};   // bias in C-in
        #pragma unroll
        for (int ks = 0; ks < 8; ++ks) {
            bf16x8 b = *(const bf16x8*)(LDS + h1 + aB1 + ks * 2048);
            acc1 = MFMA16(A[ks], b, acc1, 0, 0, 0);
        }
        #pragma unroll
        for (int r = 0; r < 4; ++r) {
            float g = gelu_fast(acc1[r]);
            *(unsigned short*)(LDS + L_HS + aW[r]) = (unsigned short)f2bf_rhu(g);
        }
        __syncthreads();   // Hs[t] visible; drains B2f loads + B1[t+1] GLLs

        // ===== PH_B: G2 16x16x32: A from Hs (2 reads), B from regs; accumulate =====
        bf16x8 a0 = *(const bf16x8*)(LDS + L_HS + aH);
        bf16x8 a1 = *(const bf16x8*)(LDS + L_HS + aH + 256);
        #pragma unroll
        for (int cf = 0; cf < 4; ++cf) {
            acc2[0][cf] = MFMA16(a0, B2f[cf], acc2[0][cf], 0, 0, 0);
            acc2[1][cf] = MFMA16(a1, B2f[cf], acc2[1][cf], 0, 0, 0);
        }
        __syncthreads();   // Hs readers done -> Hs free for G1[t+1]
    }

    // ---- epilogue: LN(256), gelu, +skip (b2 already in acc2) ----
    float sA[2][4], sQ[2][4];
    #pragma unroll
    for (int rf = 0; rf < 2; ++rf)
        #pragma unroll
        for (int r = 0; r < 4; ++r) { sA[rf][r] = 0.f; sQ[rf][r] = 0.f; }
    #pragma unroll
    for (int rf = 0; rf < 2; ++rf)
        #pragma unroll
        for (int cf = 0; cf < 4; ++cf)
            #pragma unroll
            for (int r = 0; r < 4; ++r) {
                float v = acc2[rf][cf][r];
                sA[rf][r] += v;
                sQ[rf][r] += v * v;
            }
    #pragma unroll
    for (int m = 1; m < 16; m <<= 1)
        #pragma unroll
        for (int rf = 0; rf < 2; ++rf)
            #pragma unroll
            for (int r = 0; r < 4; ++r) {
                sA[rf][r] += __shfl_xor(sA[rf][r], m, 64);
                sQ[rf][r] += __shfl_xor(sQ[rf][r], m, 64);
            }
    // partials Lred[row*4 + colg2] (s), +256 floats (sq): 2KB in Hs region
    float* Lred = (float*)(LDS + L_HS);
    if (c == 0) {
        #pragma unroll
        for (int rf = 0; rf < 2; ++rf)
            #pragma unroll
            for (int r = 0; r < 4; ++r) {
                int row = rowg2 * 32 + rf * 16 + q * 4 + r;
                Lred[row * 4 + colg2]       = sA[rf][r];
                Lred[256 + row * 4 + colg2] = sQ[rf][r];
            }
    }
    __syncthreads();
    float mu[2][4], rs[2][4];
    #pragma unroll
    for (int rf = 0; rf < 2; ++rf)
        #pragma unroll
        for (int r = 0; r < 4; ++r) {
            int row = rowg2 * 32 + rf * 16 + q * 4 + r;
            f32x4 sv = *(const f32x4*)(Lred + row * 4);        // broadcast (same addr all lanes)
            f32x4 qv = *(const f32x4*)(Lred + 256 + row * 4);
            float ssum = sv[0] + sv[1] + sv[2] + sv[3];
            float qsum = qv[0] + qv[1] + qv[2] + qv[3];
            float m_ = ssum * (1.0f / 256.0f);
            float var = qsum * (1.0f / 256.0f) - m_ * m_;
            mu[rf][r] = m_;
            rs[rf][r] = rsqrtf(var + 1e-5f);
        }
    #pragma unroll
    for (int cf = 0; cf < 4; ++cf) {
        int col = colg2 * 64 + cf * 16 + c;
        float lw = lnw[col];
        float lb = lnb[col];
        #pragma unroll
        for (int rf = 0; rf < 2; ++rf)
            #pragma unroll
            for (int r = 0; r < 4; ++r) {
                int row = rowg2 * 32 + rf * 16 + q * 4 + r;
                float v = (acc2[rf][cf][r] - mu[rf][r]) * rs[rf][r] * lw + lb;
                float g = gelu_fast(v);
                size_t oi = ((size_t)(row0 + row) * NBR + n) * DV + col;
                out[oi] = x[oi] + g;
            }
    }
#undef STAGE1
}

extern "C" void kernel_launch(void* const* d_in, const int* in_sizes, int n_in,
                              void* d_out, int out_size, void* d_ws, size_t ws_size,
                              hipStream_t stream) {
    const float* x   = (const float*)d_in[0];
    const float* U1  = (const float*)d_in[1];
    const float* b1  = (const float*)d_in[2];
    const float* U2  = (const float*)d_in[3];
    const float* b2  = (const float*)d_in[4];
    const float* lnw = (const float*)d_in[5];
    const float* lnb = (const float*)d_in[6];
    float* out = (float*)d_out;

    unsigned short* w1img = (unsigned short*)d_ws;               // 4 MB (256 x 16KB)
    unsigned short* w2img = w1img + (size_t)4 * 1024 * 1024 / 2; // 4 MB (256 x 16KB)

    prep_weights<<<dim3(256), dim3(256), 0, stream>>>(U1, U2, w1img, w2img);
    belayer_main<<<dim3((NROWS / RT) * NBR), dim3(512), 0, stream>>>(x, w1img, w2img, b1, b2, lnw, lnb, out);
}